// Round 10
// baseline (514.568 us; speedup 1.0000x reference)
//
#include <hip/hip_runtime.h>
#include <hip/hip_fp16.h>
#include <math.h>

#define NN 50000
#define NE 800000
#define C  128
#define BKT 128                                   // node ids per bucket
#define NBUK ((NN + BKT - 1) / BKT)               // 391
#define BCAP 4096                                 // slack slots per bucket

typedef _Float16 f16x8 __attribute__((ext_vector_type(8)));
typedef float f32x4 __attribute__((ext_vector_type(4)));

// ---------- prep: st zero + bcnt zero + W fp16 + x fp16 ----------
// grid must cover NN*C/4 = 1,600,000 float4 elements -> 6250 blocks of 256
__global__ __launch_bounds__(256) void k_prep(const float* __restrict__ x,
                     __half2* __restrict__ xh,
                     const float* __restrict__ W1, const float* __restrict__ W2,
                     _Float16* __restrict__ Wh1, _Float16* __restrict__ Wh2,
                     int* __restrict__ bcnt, double* __restrict__ st) {
  int i = blockIdx.x * 256 + threadIdx.x;
  if (i < NN * C / 4) {
    float4 v = ((const float4*)x)[i];
    xh[2 * i]     = __floats2half2_rn(v.x, v.y);
    xh[2 * i + 1] = __floats2half2_rn(v.z, v.w);
  }
  if (i < C * C) Wh1[i] = (_Float16)W1[i];
  else if (i < 2 * C * C) Wh2[i - C * C] = (_Float16)W2[i - C * C];
  if (i < NBUK) bcnt[i] = 0;
  if (i == NBUK) { st[0] = 0.0; st[1] = 0.0; }
}

// ---------- scatter into slack buckets via hot atomics ----------
__global__ __launch_bounds__(256) void k_scat(const int* __restrict__ src,
                     const int* __restrict__ dst,
                     int* __restrict__ bcnt, int2* __restrict__ binned) {
  int i = blockIdx.x * 256 + threadIdx.x;
  if (i < NE / 4) {
    int4 s = ((const int4*)src)[i];
    int4 d = ((const int4*)dst)[i];
    int b0 = d.x >> 7, b1 = d.y >> 7, b2 = d.z >> 7, b3 = d.w >> 7;
    int p0 = atomicAdd(&bcnt[b0], 1);
    int p1 = atomicAdd(&bcnt[b1], 1);
    int p2 = atomicAdd(&bcnt[b2], 1);
    int p3 = atomicAdd(&bcnt[b3], 1);
    if (p0 < BCAP) binned[b0 * BCAP + p0] = make_int2(s.x, d.x);
    if (p1 < BCAP) binned[b1 * BCAP + p1] = make_int2(s.y, d.y);
    if (p2 < BCAP) binned[b2 * BCAP + p2] = make_int2(s.z, d.z);
    if (p3 < BCAP) binned[b3 * BCAP + p3] = make_int2(s.w, d.w);
  }
}

// ---------- per-bucket CSR fill: LDS hist+scan -> rowstart, deg, csr ----------
__global__ __launch_bounds__(256) void k_bfill2(const int2* __restrict__ binned,
                     const int* __restrict__ bcnt,
                     int* __restrict__ rowstart, int* __restrict__ deg,
                     int* __restrict__ csr) {
  int b = blockIdx.x, t = threadIdx.x;
  __shared__ int hist[BKT];
  __shared__ int cur[BKT];
  __shared__ int wsum[4];
  int cnt = bcnt[b];
  if (cnt > BCAP) cnt = BCAP;
  int base = b * BCAP;
  if (t < BKT) hist[t] = 0;
  __syncthreads();
  for (int j = t; j < cnt; j += 256) atomicAdd(&hist[binned[base + j].y & (BKT - 1)], 1);
  __syncthreads();
  int v = (t < BKT) ? hist[t] : 0;
  int lane = t & 63, wid = t >> 6;
  int incl = v;
  #pragma unroll
  for (int off = 1; off < 64; off <<= 1) {
    int u = __shfl_up(incl, off, 64);
    if (lane >= off) incl += u;
  }
  if (lane == 63) wsum[wid] = incl;
  __syncthreads();
  int woff = 0;
  #pragma unroll
  for (int wI = 0; wI < 4; ++wI) if (wI < wid) woff += wsum[wI];
  int excl = woff + incl - v;
  if (t < BKT) {
    cur[t] = excl;
    int node = b * BKT + t;
    if (node < NN) { rowstart[node] = base + excl; deg[node] = v; }
  }
  __syncthreads();
  for (int j = t; j < cnt; j += 256) {
    int2 sd = binned[base + j];
    int p = atomicAdd(&cur[sd.y & (BKT - 1)], 1);
    csr[base + p] = sd.x;
  }
}

// ---------- aggregation: one wave per node, fp16 gather, 8-deep unroll ----------
__global__ __launch_bounds__(256) void k_agg_h(const __half2* __restrict__ xh2,
                       const int* __restrict__ rs, const int* __restrict__ degp,
                       const int* __restrict__ csr,
                       const float* __restrict__ eps_p, __half2* __restrict__ preh2) {
  int wid = threadIdx.x >> 6;
  int lane = threadIdx.x & 63;
  int n = blockIdx.x * 4 + wid;
  if (n >= NN) return;
  int s0 = rs[n];
  int dg = degp[n];
  int s1 = s0 + dg;
  float a0 = -INFINITY, a1 = -INFINITY, b0 = -INFINITY, b1 = -INFINITY;
  float c0 = -INFINITY, c1 = -INFINITY, d0 = -INFINITY, d1 = -INFINITY;
  float e0a = -INFINITY, e1a = -INFINITY, f0 = -INFINITY, f1 = -INFINITY;
  float g0 = -INFINITY, g1 = -INFINITY, h0 = -INFINITY, h1 = -INFINITY;
  int j = s0;
  for (; j + 7 < s1; j += 8) {
    int i0 = csr[j], i1 = csr[j + 1], i2 = csr[j + 2], i3 = csr[j + 3];
    int i4 = csr[j + 4], i5 = csr[j + 5], i6 = csr[j + 6], i7 = csr[j + 7];
    __half2 v0 = xh2[(size_t)i0 * 64 + lane];
    __half2 v1 = xh2[(size_t)i1 * 64 + lane];
    __half2 v2 = xh2[(size_t)i2 * 64 + lane];
    __half2 v3 = xh2[(size_t)i3 * 64 + lane];
    __half2 v4 = xh2[(size_t)i4 * 64 + lane];
    __half2 v5 = xh2[(size_t)i5 * 64 + lane];
    __half2 v6 = xh2[(size_t)i6 * 64 + lane];
    __half2 v7 = xh2[(size_t)i7 * 64 + lane];
    a0 = fmaxf(a0, __low2float(v0));  a1 = fmaxf(a1, __high2float(v0));
    b0 = fmaxf(b0, __low2float(v1));  b1 = fmaxf(b1, __high2float(v1));
    c0 = fmaxf(c0, __low2float(v2));  c1 = fmaxf(c1, __high2float(v2));
    d0 = fmaxf(d0, __low2float(v3));  d1 = fmaxf(d1, __high2float(v3));
    e0a = fmaxf(e0a, __low2float(v4)); e1a = fmaxf(e1a, __high2float(v4));
    f0 = fmaxf(f0, __low2float(v5));  f1 = fmaxf(f1, __high2float(v5));
    g0 = fmaxf(g0, __low2float(v6));  g1 = fmaxf(g1, __high2float(v6));
    h0 = fmaxf(h0, __low2float(v7));  h1 = fmaxf(h1, __high2float(v7));
  }
  for (; j + 3 < s1; j += 4) {
    int i0 = csr[j], i1 = csr[j + 1], i2 = csr[j + 2], i3 = csr[j + 3];
    __half2 v0 = xh2[(size_t)i0 * 64 + lane];
    __half2 v1 = xh2[(size_t)i1 * 64 + lane];
    __half2 v2 = xh2[(size_t)i2 * 64 + lane];
    __half2 v3 = xh2[(size_t)i3 * 64 + lane];
    a0 = fmaxf(a0, __low2float(v0)); a1 = fmaxf(a1, __high2float(v0));
    b0 = fmaxf(b0, __low2float(v1)); b1 = fmaxf(b1, __high2float(v1));
    c0 = fmaxf(c0, __low2float(v2)); c1 = fmaxf(c1, __high2float(v2));
    d0 = fmaxf(d0, __low2float(v3)); d1 = fmaxf(d1, __high2float(v3));
  }
  for (; j < s1; ++j) {
    int i0 = csr[j];
    __half2 v0 = xh2[(size_t)i0 * 64 + lane];
    a0 = fmaxf(a0, __low2float(v0)); a1 = fmaxf(a1, __high2float(v0));
  }
  float m0 = fmaxf(fmaxf(fmaxf(a0, b0), fmaxf(c0, d0)), fmaxf(fmaxf(e0a, f0), fmaxf(g0, h0)));
  float m1 = fmaxf(fmaxf(fmaxf(a1, b1), fmaxf(c1, d1)), fmaxf(fmaxf(e1a, f1), fmaxf(g1, h1)));
  if (dg == 0) { m0 = 0.f; m1 = 0.f; }   // empty segment -> 0 (PyG fill)
  float e1v = 1.0f + eps_p[0];
  __half2 xs = xh2[(size_t)n * 64 + lane];
  float ox = fmaf(e1v, __low2float(xs), m0);
  float oy = fmaf(e1v, __high2float(xs), m1);
  preh2[(size_t)n * 64 + lane] = __floats2half2_rn(ox, oy);
}

// ---------- MFMA GEMM; MODE 0: fp16 h out + LN stats; MODE 1: fp32 out (nt) ----------
template<int MODE>
__global__ __launch_bounds__(256) void k_gemm_f16(const _Float16* __restrict__ Ah,
                       const _Float16* __restrict__ Wh, const float* __restrict__ bias,
                       _Float16* __restrict__ outh, float* __restrict__ outf,
                       double* __restrict__ st) {
  int wid = threadIdx.x >> 6, lane = threadIdx.x & 63;
  int nt = blockIdx.x * 4 + wid;          // 16-node tile id
  int r = lane & 15;
  int kq = lane >> 4;
  float s = 0.f, ss = 0.f;
  if (nt < NN / 16) {                     // 3125 tiles exactly
    const _Float16* arow = Ah + ((size_t)nt * 16 + r) * C + kq * 8;
    f32x4 acc[8];
    #pragma unroll
    for (int ot = 0; ot < 8; ++ot) {
      float bv = bias[ot * 16 + r];
      f32x4 z = {bv, bv, bv, bv};
      acc[ot] = z;
    }
    #pragma unroll
    for (int kk = 0; kk < 4; ++kk) {
      f16x8 a = *(const f16x8*)(arow + kk * 32);
      #pragma unroll
      for (int ot = 0; ot < 8; ++ot) {
        f16x8 b = *(const f16x8*)(Wh + ((size_t)ot * 16 + r) * C + kk * 32 + kq * 8);
        acc[ot] = __builtin_amdgcn_mfma_f32_16x16x32_f16(a, b, acc[ot], 0, 0, 0);
      }
    }
    size_t nbase = (size_t)nt * 16;
    #pragma unroll
    for (int ot = 0; ot < 8; ++ot) {
      #pragma unroll
      for (int j = 0; j < 4; ++j) {
        float v = acc[ot][j];
        size_t off = (nbase + kq * 4 + j) * C + ot * 16 + r;
        if (MODE == 0) {
          outh[off] = (_Float16)v;
          s += v; ss += v * v;
        } else {
          __builtin_nontemporal_store(v, &outf[off]);
        }
      }
    }
  }
  if (MODE == 0) {
    #pragma unroll
    for (int off = 32; off > 0; off >>= 1) {
      s  += __shfl_down(s, off, 64);
      ss += __shfl_down(ss, off, 64);
    }
    __shared__ float sdl[4], ssl[4];
    if (lane == 0) { sdl[wid] = s; ssl[wid] = ss; }
    __syncthreads();
    if (threadIdx.x == 0) {
      atomicAdd(&st[0], (double)(sdl[0] + sdl[1] + sdl[2] + sdl[3]));
      atomicAdd(&st[1], (double)(ssl[0] + ssl[1] + ssl[2] + ssl[3]));
    }
  }
}

// ---------- LN finalize + apply + PReLU: fp16 in -> fp16 out ----------
__global__ __launch_bounds__(256) void k_act_h(const _Float16* __restrict__ h,
                       const double* __restrict__ st,
                       const float* __restrict__ lw, const float* __restrict__ lb,
                       const float* __restrict__ a_p, _Float16* __restrict__ outh) {
  int i = blockIdx.x * 256 + threadIdx.x;   // f16x8 index, total NN*C/8 = 800000
  if (i >= NN * C / 8) return;
  const double M = (double)NN * C;
  double meand = st[0] / M;
  double var = st[1] / M - meand * meand;
  if (var < 0.0) var = 0.0;
  float mean = (float)meand;
  float inv = (float)(1.0 / (sqrt(var) + 1e-5));
  float a = a_p[0];
  f16x8 v = ((const f16x8*)h)[i];
  int c8 = i & 15;                          // channel-octet
  float4 w0 = ((const float4*)lw)[c8 * 2], w1 = ((const float4*)lw)[c8 * 2 + 1];
  float4 b0 = ((const float4*)lb)[c8 * 2], b1 = ((const float4*)lb)[c8 * 2 + 1];
  float wv[8] = {w0.x, w0.y, w0.z, w0.w, w1.x, w1.y, w1.z, w1.w};
  float bv[8] = {b0.x, b0.y, b0.z, b0.w, b1.x, b1.y, b1.z, b1.w};
  f16x8 res;
  #pragma unroll
  for (int k = 0; k < 8; ++k) {
    float r = ((float)v[k] - mean) * inv * wv[k] + bv[k];
    r = (r >= 0.f) ? r : a * r;
    res[k] = (_Float16)r;
  }
  ((f16x8*)outh)[i] = res;
}

extern "C" void kernel_launch(void* const* d_in, const int* in_sizes, int n_in,
                              void* d_out, int out_size, void* d_ws, size_t ws_size,
                              hipStream_t stream) {
  const float* x    = (const float*)d_in[0];
  const int*   ei   = (const int*)d_in[1];
  const float* eps1 = (const float*)d_in[2];
  const float* W1   = (const float*)d_in[3];
  const float* b1   = (const float*)d_in[4];
  const float* lnw  = (const float*)d_in[5];
  const float* lnb  = (const float*)d_in[6];
  const float* pa   = (const float*)d_in[7];
  const float* eps2 = (const float*)d_in[8];
  const float* W2   = (const float*)d_in[9];
  const float* b2   = (const float*)d_in[10];
  float* out = (float*)d_out;
  const int* srcI = ei;         // edge_index[0]
  const int* dstI = ei + NE;    // edge_index[1]

  char* w = (char*)d_ws;
  _Float16* Bh     = (_Float16*)(w);               // 12,800,000 B (h fp16)
  __half2*  xh     = (__half2*)(w + 12800000);     // 12,800,000 B (gather table)
  __half2*  preh   = (__half2*)(w + 25600000);     // 12,800,000 B (agg out / gemm A)
  _Float16* Wh1    = (_Float16*)(w + 38400000);    // 32,768 B
  _Float16* Wh2    = (_Float16*)(w + 38432768);    // 32,768 B
  int*      rowst  = (int*)(w + 38465536);         // 200,000 B
  int*      deg    = (int*)(w + 38665536);         // 200,000 B
  int*      csr    = (int*)(w + 38865536);         // 6,406,144 B (slack)
  int2*     binned = (int2*)(w + 45271680);        // 12,812,288 B (slack)
  int*      bcnt   = (int*)(w + 58083968);         // 1,564 B
  double*   st     = (double*)(w + 58085536);      // 16 B

  // 1: prep (st/bcnt zero, W fp16, x fp16) — grid covers 1.6M float4
  k_prep<<<6250, 256, 0, stream>>>(x, xh, W1, W2, Wh1, Wh2, bcnt, st);
  // 2-3: CSR build (slack buckets)
  k_scat<<<(NE / 4 + 255) / 256, 256, 0, stream>>>(srcI, dstI, bcnt, binned);
  k_bfill2<<<NBUK, 256, 0, stream>>>(binned, bcnt, rowst, deg, csr);
  // 4-5: layer 1
  k_agg_h<<<(NN + 3) / 4, 256, 0, stream>>>(xh, rowst, deg, csr, eps1, preh);
  k_gemm_f16<0><<<(NN / 16 + 3) / 4, 256, 0, stream>>>((const _Float16*)preh, Wh1, b1,
                                                       Bh, nullptr, st);
  // 6: LN finalize + apply + PReLU -> new fp16 gather table
  k_act_h<<<(NN * C / 8 + 255) / 256, 256, 0, stream>>>(Bh, st, lnw, lnb, pa,
                                                        (_Float16*)xh);
  // 7-8: layer 2
  k_agg_h<<<(NN + 3) / 4, 256, 0, stream>>>(xh, rowst, deg, csr, eps2, preh);
  k_gemm_f16<1><<<(NN / 16 + 3) / 4, 256, 0, stream>>>((const _Float16*)preh, Wh2, b2,
                                                       nullptr, out, nullptr);
}

// Round 11
// 250.264 us; speedup vs baseline: 2.0561x; 2.0561x over previous
//
#include <hip/hip_runtime.h>
#include <hip/hip_fp16.h>
#include <math.h>

#define NN 50000
#define NE 800000
#define C  128
#define BKT 128                                   // node ids per bucket
#define NBUK ((NN + BKT - 1) / BKT)               // 391
#define ECHUNK 2048                               // edges per partition chunk
#define NEBLK ((NE + ECHUNK - 1) / ECHUNK)        // 391

typedef _Float16 f16x8 __attribute__((ext_vector_type(8)));
typedef float f32x4 __attribute__((ext_vector_type(4)));

// ---------- prep: st zero + W fp16 + x fp16 + (blocks<NEBLK) bucket histogram ----------
// grid covers NN*C/4 = 1,600,000 float4 -> 6250 blocks of 256
__global__ __launch_bounds__(256) void k_prep(const float* __restrict__ x,
                     __half2* __restrict__ xh,
                     const float* __restrict__ W1, const float* __restrict__ W2,
                     _Float16* __restrict__ Wh1, _Float16* __restrict__ Wh2,
                     const int* __restrict__ dst, int* __restrict__ bh,
                     double* __restrict__ st) {
  int t = threadIdx.x;
  int i = blockIdx.x * 256 + t;
  if (i < NN * C / 4) {
    float4 v = ((const float4*)x)[i];
    xh[2 * i]     = __floats2half2_rn(v.x, v.y);
    xh[2 * i + 1] = __floats2half2_rn(v.z, v.w);
  }
  if (i < C * C) Wh1[i] = (_Float16)W1[i];
  else if (i < 2 * C * C) Wh2[i - C * C] = (_Float16)W2[i - C * C];
  if (i == 0) { st[0] = 0.0; st[1] = 0.0; }
  // bucket histogram for CSR multisplit (chunk = this block)
  if (blockIdx.x < NEBLK) {
    __shared__ int h[NBUK];
    for (int k = t; k < NBUK; k += 256) h[k] = 0;
    __syncthreads();
    int base = blockIdx.x * ECHUNK;
    int end = base + ECHUNK; if (end > NE) end = NE;
    for (int e = base + t; e < end; e += 256) atomicAdd(&h[dst[e] >> 7], 1);
    __syncthreads();
    for (int k = t; k < NBUK; k += 256) bh[k * NEBLK + blockIdx.x] = h[k];
  }
}

// ---------- per-bucket exclusive scan over chunk counts ----------
__global__ __launch_bounds__(256) void k_bscan(int* __restrict__ bh,
                                               int* __restrict__ btot) {
  int b = blockIdx.x, t = threadIdx.x;
  int lane = t & 63, wid = t >> 6;
  __shared__ int wsum[4];
  int carry = 0;
  for (int base = 0; base < NEBLK; base += 256) {
    int i = base + t;
    int v = (i < NEBLK) ? bh[b * NEBLK + i] : 0;
    int incl = v;
    #pragma unroll
    for (int off = 1; off < 64; off <<= 1) {
      int u = __shfl_up(incl, off, 64);
      if (lane >= off) incl += u;
    }
    if (lane == 63) wsum[wid] = incl;
    __syncthreads();
    int woff = 0;
    #pragma unroll
    for (int wI = 0; wI < 4; ++wI) if (wI < wid) woff += wsum[wI];
    if (i < NEBLK) bh[b * NEBLK + i] = carry + woff + incl - v;
    int total = wsum[0] + wsum[1] + wsum[2] + wsum[3];
    __syncthreads();
    carry += total;
  }
  if (t == 0) btot[b] = carry;
}

// ---------- scan bucket totals -> bucket bases ----------
__global__ __launch_bounds__(256) void k_bbase(const int* __restrict__ btot,
                                               int* __restrict__ bbase,
                                               int* __restrict__ rowstart) {
  int t = threadIdx.x;
  int lane = t & 63, wid = t >> 6;
  __shared__ int wsum[4];
  int carry = 0;
  for (int base = 0; base < NBUK; base += 256) {
    int i = base + t;
    int v = (i < NBUK) ? btot[i] : 0;
    int incl = v;
    #pragma unroll
    for (int off = 1; off < 64; off <<= 1) {
      int u = __shfl_up(incl, off, 64);
      if (lane >= off) incl += u;
    }
    if (lane == 63) wsum[wid] = incl;
    __syncthreads();
    int woff = 0;
    #pragma unroll
    for (int wI = 0; wI < 4; ++wI) if (wI < wid) woff += wsum[wI];
    if (i < NBUK) bbase[i] = carry + woff + incl - v;
    int total = wsum[0] + wsum[1] + wsum[2] + wsum[3];
    __syncthreads();
    carry += total;
  }
  if (t == 0) rowstart[NN] = NE;
}

// ---------- scatter edges into bucket-major binned array (LDS cursors) ----------
__global__ __launch_bounds__(256) void k_bscatter(const int* __restrict__ src,
                       const int* __restrict__ dst,
                       const int* __restrict__ bh, const int* __restrict__ bbase,
                       int2* __restrict__ binned) {
  __shared__ int cur[NBUK];
  int t = threadIdx.x, blk = blockIdx.x;
  for (int i = t; i < NBUK; i += 256) cur[i] = bbase[i] + bh[i * NEBLK + blk];
  __syncthreads();
  int base = blk * ECHUNK;
  int end = base + ECHUNK; if (end > NE) end = NE;
  for (int e = base + t; e < end; e += 256) {
    int d = dst[e];
    int pos = atomicAdd(&cur[d >> 7], 1);
    binned[pos] = make_int2(src[e], d);
  }
}

// ---------- per-bucket CSR fill + rowstart (LDS hist+scan) ----------
__global__ __launch_bounds__(256) void k_bfill(const int2* __restrict__ binned,
                       const int* __restrict__ bbase, const int* __restrict__ btot,
                       int* __restrict__ rowstart, int* __restrict__ csr) {
  int b = blockIdx.x, t = threadIdx.x;
  __shared__ int hist[BKT];
  __shared__ int cur[BKT];
  __shared__ int wsum[4];
  int s0 = bbase[b];
  int cnt = btot[b];
  if (t < BKT) hist[t] = 0;
  __syncthreads();
  for (int j = t; j < cnt; j += 256) atomicAdd(&hist[binned[s0 + j].y & (BKT - 1)], 1);
  __syncthreads();
  int v = (t < BKT) ? hist[t] : 0;
  int lane = t & 63, wid = t >> 6;
  int incl = v;
  #pragma unroll
  for (int off = 1; off < 64; off <<= 1) {
    int u = __shfl_up(incl, off, 64);
    if (lane >= off) incl += u;
  }
  if (lane == 63) wsum[wid] = incl;
  __syncthreads();
  int woff = 0;
  #pragma unroll
  for (int wI = 0; wI < 4; ++wI) if (wI < wid) woff += wsum[wI];
  int excl = woff + incl - v;
  if (t < BKT) {
    cur[t] = excl;
    int node = b * BKT + t;
    if (node < NN) rowstart[node] = s0 + excl;
  }
  __syncthreads();
  for (int j = t; j < cnt; j += 256) {
    int2 sd = binned[s0 + j];
    int p = atomicAdd(&cur[sd.y & (BKT - 1)], 1);
    csr[s0 + p] = sd.x;
  }
}

// ---------- aggregation: one wave per node, fp16 gather, 8-deep unroll ----------
__global__ __launch_bounds__(256) void k_agg_h(const __half2* __restrict__ xh2,
                       const int* __restrict__ rs, const int* __restrict__ csr,
                       const float* __restrict__ eps_p, __half2* __restrict__ preh2) {
  int wid = threadIdx.x >> 6;
  int lane = threadIdx.x & 63;
  int n = blockIdx.x * 4 + wid;
  if (n >= NN) return;
  int s0 = rs[n], s1 = rs[n + 1];
  float a0 = -INFINITY, a1 = -INFINITY, b0 = -INFINITY, b1 = -INFINITY;
  float c0 = -INFINITY, c1 = -INFINITY, d0 = -INFINITY, d1 = -INFINITY;
  float e0a = -INFINITY, e1a = -INFINITY, f0 = -INFINITY, f1 = -INFINITY;
  float g0 = -INFINITY, g1 = -INFINITY, h0 = -INFINITY, h1 = -INFINITY;
  int j = s0;
  for (; j + 7 < s1; j += 8) {
    int i0 = csr[j], i1 = csr[j + 1], i2 = csr[j + 2], i3 = csr[j + 3];
    int i4 = csr[j + 4], i5 = csr[j + 5], i6 = csr[j + 6], i7 = csr[j + 7];
    __half2 v0 = xh2[(size_t)i0 * 64 + lane];
    __half2 v1 = xh2[(size_t)i1 * 64 + lane];
    __half2 v2 = xh2[(size_t)i2 * 64 + lane];
    __half2 v3 = xh2[(size_t)i3 * 64 + lane];
    __half2 v4 = xh2[(size_t)i4 * 64 + lane];
    __half2 v5 = xh2[(size_t)i5 * 64 + lane];
    __half2 v6 = xh2[(size_t)i6 * 64 + lane];
    __half2 v7 = xh2[(size_t)i7 * 64 + lane];
    a0 = fmaxf(a0, __low2float(v0));  a1 = fmaxf(a1, __high2float(v0));
    b0 = fmaxf(b0, __low2float(v1));  b1 = fmaxf(b1, __high2float(v1));
    c0 = fmaxf(c0, __low2float(v2));  c1 = fmaxf(c1, __high2float(v2));
    d0 = fmaxf(d0, __low2float(v3));  d1 = fmaxf(d1, __high2float(v3));
    e0a = fmaxf(e0a, __low2float(v4)); e1a = fmaxf(e1a, __high2float(v4));
    f0 = fmaxf(f0, __low2float(v5));  f1 = fmaxf(f1, __high2float(v5));
    g0 = fmaxf(g0, __low2float(v6));  g1 = fmaxf(g1, __high2float(v6));
    h0 = fmaxf(h0, __low2float(v7));  h1 = fmaxf(h1, __high2float(v7));
  }
  for (; j + 3 < s1; j += 4) {
    int i0 = csr[j], i1 = csr[j + 1], i2 = csr[j + 2], i3 = csr[j + 3];
    __half2 v0 = xh2[(size_t)i0 * 64 + lane];
    __half2 v1 = xh2[(size_t)i1 * 64 + lane];
    __half2 v2 = xh2[(size_t)i2 * 64 + lane];
    __half2 v3 = xh2[(size_t)i3 * 64 + lane];
    a0 = fmaxf(a0, __low2float(v0)); a1 = fmaxf(a1, __high2float(v0));
    b0 = fmaxf(b0, __low2float(v1)); b1 = fmaxf(b1, __high2float(v1));
    c0 = fmaxf(c0, __low2float(v2)); c1 = fmaxf(c1, __high2float(v2));
    d0 = fmaxf(d0, __low2float(v3)); d1 = fmaxf(d1, __high2float(v3));
  }
  for (; j < s1; ++j) {
    int i0 = csr[j];
    __half2 v0 = xh2[(size_t)i0 * 64 + lane];
    a0 = fmaxf(a0, __low2float(v0)); a1 = fmaxf(a1, __high2float(v0));
  }
  float m0 = fmaxf(fmaxf(fmaxf(a0, b0), fmaxf(c0, d0)), fmaxf(fmaxf(e0a, f0), fmaxf(g0, h0)));
  float m1 = fmaxf(fmaxf(fmaxf(a1, b1), fmaxf(c1, d1)), fmaxf(fmaxf(e1a, f1), fmaxf(g1, h1)));
  if (s1 == s0) { m0 = 0.f; m1 = 0.f; }   // empty segment -> 0 (PyG fill)
  float e1v = 1.0f + eps_p[0];
  __half2 xs = xh2[(size_t)n * 64 + lane];
  float ox = fmaf(e1v, __low2float(xs), m0);
  float oy = fmaf(e1v, __high2float(xs), m1);
  preh2[(size_t)n * 64 + lane] = __floats2half2_rn(ox, oy);
}

// ---------- MFMA GEMM; MODE 0: fp16 h out + LN stats; MODE 1: fp32 out (nt) ----------
template<int MODE>
__global__ __launch_bounds__(256) void k_gemm_f16(const _Float16* __restrict__ Ah,
                       const _Float16* __restrict__ Wh, const float* __restrict__ bias,
                       _Float16* __restrict__ outh, float* __restrict__ outf,
                       double* __restrict__ st) {
  int wid = threadIdx.x >> 6, lane = threadIdx.x & 63;
  int nt = blockIdx.x * 4 + wid;          // 16-node tile id
  int r = lane & 15;
  int kq = lane >> 4;
  float s = 0.f, ss = 0.f;
  if (nt < NN / 16) {                     // 3125 tiles exactly
    const _Float16* arow = Ah + ((size_t)nt * 16 + r) * C + kq * 8;
    f32x4 acc[8];
    #pragma unroll
    for (int ot = 0; ot < 8; ++ot) {
      float bv = bias[ot * 16 + r];
      f32x4 z = {bv, bv, bv, bv};
      acc[ot] = z;
    }
    #pragma unroll
    for (int kk = 0; kk < 4; ++kk) {
      f16x8 a = *(const f16x8*)(arow + kk * 32);
      #pragma unroll
      for (int ot = 0; ot < 8; ++ot) {
        f16x8 b = *(const f16x8*)(Wh + ((size_t)ot * 16 + r) * C + kk * 32 + kq * 8);
        acc[ot] = __builtin_amdgcn_mfma_f32_16x16x32_f16(a, b, acc[ot], 0, 0, 0);
      }
    }
    size_t nbase = (size_t)nt * 16;
    #pragma unroll
    for (int ot = 0; ot < 8; ++ot) {
      #pragma unroll
      for (int j = 0; j < 4; ++j) {
        float v = acc[ot][j];
        size_t off = (nbase + kq * 4 + j) * C + ot * 16 + r;
        if (MODE == 0) {
          outh[off] = (_Float16)v;
          s += v; ss += v * v;
        } else {
          __builtin_nontemporal_store(v, &outf[off]);
        }
      }
    }
  }
  if (MODE == 0) {
    #pragma unroll
    for (int off = 32; off > 0; off >>= 1) {
      s  += __shfl_down(s, off, 64);
      ss += __shfl_down(ss, off, 64);
    }
    __shared__ float sdl[4], ssl[4];
    if (lane == 0) { sdl[wid] = s; ssl[wid] = ss; }
    __syncthreads();
    if (threadIdx.x == 0) {
      atomicAdd(&st[0], (double)(sdl[0] + sdl[1] + sdl[2] + sdl[3]));
      atomicAdd(&st[1], (double)(ssl[0] + ssl[1] + ssl[2] + ssl[3]));
    }
  }
}

// ---------- LN finalize + apply + PReLU: fp16 in -> fp16 out ----------
__global__ __launch_bounds__(256) void k_act_h(const _Float16* __restrict__ h,
                       const double* __restrict__ st,
                       const float* __restrict__ lw, const float* __restrict__ lb,
                       const float* __restrict__ a_p, _Float16* __restrict__ outh) {
  int i = blockIdx.x * 256 + threadIdx.x;   // f16x8 index, total NN*C/8 = 800000
  if (i >= NN * C / 8) return;
  const double M = (double)NN * C;
  double meand = st[0] / M;
  double var = st[1] / M - meand * meand;
  if (var < 0.0) var = 0.0;
  float mean = (float)meand;
  float inv = (float)(1.0 / (sqrt(var) + 1e-5));
  float a = a_p[0];
  f16x8 v = ((const f16x8*)h)[i];
  int c8 = i & 15;                          // channel-octet
  float4 w0 = ((const float4*)lw)[c8 * 2], w1 = ((const float4*)lw)[c8 * 2 + 1];
  float4 b0 = ((const float4*)lb)[c8 * 2], b1 = ((const float4*)lb)[c8 * 2 + 1];
  float wv[8] = {w0.x, w0.y, w0.z, w0.w, w1.x, w1.y, w1.z, w1.w};
  float bv[8] = {b0.x, b0.y, b0.z, b0.w, b1.x, b1.y, b1.z, b1.w};
  f16x8 res;
  #pragma unroll
  for (int k = 0; k < 8; ++k) {
    float r = ((float)v[k] - mean) * inv * wv[k] + bv[k];
    r = (r >= 0.f) ? r : a * r;
    res[k] = (_Float16)r;
  }
  ((f16x8*)outh)[i] = res;
}

extern "C" void kernel_launch(void* const* d_in, const int* in_sizes, int n_in,
                              void* d_out, int out_size, void* d_ws, size_t ws_size,
                              hipStream_t stream) {
  const float* x    = (const float*)d_in[0];
  const int*   ei   = (const int*)d_in[1];
  const float* eps1 = (const float*)d_in[2];
  const float* W1   = (const float*)d_in[3];
  const float* b1   = (const float*)d_in[4];
  const float* lnw  = (const float*)d_in[5];
  const float* lnb  = (const float*)d_in[6];
  const float* pa   = (const float*)d_in[7];
  const float* eps2 = (const float*)d_in[8];
  const float* W2   = (const float*)d_in[9];
  const float* b2   = (const float*)d_in[10];
  float* out = (float*)d_out;
  const int* srcI = ei;         // edge_index[0]
  const int* dstI = ei + NE;    // edge_index[1]

  char* w = (char*)d_ws;
  _Float16* Bh     = (_Float16*)(w);               // 12,800,000 B (h fp16)
  __half2*  xh     = (__half2*)(w + 12800000);     // 12,800,000 B (gather table)
  __half2*  preh   = (__half2*)(w + 25600000);     // 12,800,000 B (agg out / gemm A)
  _Float16* Wh1    = (_Float16*)(w + 38400000);    // 32,768 B
  _Float16* Wh2    = (_Float16*)(w + 38432768);    // 32,768 B
  int*      rowst  = (int*)(w + 38465536);         // 200,064 B (N+1 ints)
  int*      csr    = (int*)(w + 38665600);         // 3,200,000 B
  int2*     binned = (int2*)(w + 41865600);        // 6,400,000 B
  int*      bh     = (int*)(w + 48265600);         // 611,584 B (NBUK*NEBLK ints)
  int*      btot   = (int*)(w + 48877184);         // 1,664 B
  int*      bbase  = (int*)(w + 48878848);         // 1,664 B
  double*   st     = (double*)(w + 48880512);      // 16 B

  // 1: prep (st zero, W fp16, x fp16, bucket histogram)
  k_prep<<<6250, 256, 0, stream>>>(x, xh, W1, W2, Wh1, Wh2, dstI, bh, st);
  // 2-5: CSR build (deterministic chunk-scan multisplit)
  k_bscan<<<NBUK, 256, 0, stream>>>(bh, btot);
  k_bbase<<<1, 256, 0, stream>>>(btot, bbase, rowst);
  k_bscatter<<<NEBLK, 256, 0, stream>>>(srcI, dstI, bh, bbase, binned);
  k_bfill<<<NBUK, 256, 0, stream>>>(binned, bbase, btot, rowst, csr);
  // 6-7: layer 1
  k_agg_h<<<(NN + 3) / 4, 256, 0, stream>>>(xh, rowst, csr, eps1, preh);
  k_gemm_f16<0><<<(NN / 16 + 3) / 4, 256, 0, stream>>>((const _Float16*)preh, Wh1, b1,
                                                       Bh, nullptr, st);
  // 8: LN finalize + apply + PReLU -> new fp16 gather table
  k_act_h<<<(NN * C / 8 + 255) / 256, 256, 0, stream>>>(Bh, st, lnw, lnb, pa,
                                                        (_Float16*)xh);
  // 9-10: layer 2
  k_agg_h<<<(NN + 3) / 4, 256, 0, stream>>>(xh, rowst, csr, eps2, preh);
  k_gemm_f16<1><<<(NN / 16 + 3) / 4, 256, 0, stream>>>((const _Float16*)preh, Wh2, b2,
                                                       nullptr, out, nullptr);
}